// Round 8
// baseline (437.513 us; speedup 1.0000x reference)
//
#include <hip/hip_runtime.h>

// Multi-head attention, B=4 S=2048 D=768 H=8 DH=96. FP32 I/O, f16 MFMA compute.
// R16: attn rewritten as in-block KV-split: 512thr/8 waves, waves 0-3 do KV
//      tiles 0-15, waves 4-7 tiles 16-31, SAME 128 q-rows (32 q/wave, 2 mf
//      groups -> each K/V LDS fragment feeds 2 MFMAs, -43% LDS traffic/MFMA).
//      Grid (16,32)=512 blocks, 2 blocks/CU, 16 waves/CU (fixes R2's occupancy
//      collapse). Single K/V buffer per group; half-k P buffer (write kf0-1,
//      PV ks=0, overwrite kf2-3, PV ks=1 -- wave-local). LDS 74.8KB.
//      Epilogue: flash-combine merge of group partials via LDS scratch.
//      GEMMs/prep unchanged from R7 (clean A/B).
// Buffers: ws = [WqT|WkT|WvT|WoT (4.7MB) | Q16 | Xk16 | Xv16 | Xq16] = 55.05MB
//          A16 overlays Xk16 after gemm_qkv (d_in never written).
//          d_out = [VT (12.6MB) | K16 (12.6MB)] f16 until GEMM_O overwrites.

typedef unsigned short u16;
typedef _Float16 h16;
typedef h16 h16x8 __attribute__((ext_vector_type(8)));
typedef __fp16 fp16x2 __attribute__((ext_vector_type(2)));
typedef __fp16 fp16x4 __attribute__((ext_vector_type(4)));
typedef unsigned short u16x8 __attribute__((ext_vector_type(8)));
typedef unsigned short u16x4 __attribute__((ext_vector_type(4)));
typedef float f32x4 __attribute__((ext_vector_type(4)));

__device__ __forceinline__ u16 f2h(float f) {
  union { h16 h; u16 u; } c; c.h = (h16)f; return c.u;
}

__device__ __forceinline__ void gll16(const void* g, void* l) {
  __builtin_amdgcn_global_load_lds(
      (const __attribute__((address_space(1))) void*)g,
      (__attribute__((address_space(3))) void*)l, 16, 0, 0);
}

// ---------------------------------------------------------------------------
// prep: LDS-tiled weight transposes + X f16 conversions (unchanged).
// ---------------------------------------------------------------------------
__global__ __launch_bounds__(256) void prep_kernel(
    const float* __restrict__ Wq, const float* __restrict__ Wk,
    const float* __restrict__ Wv, const float* __restrict__ Wo,
    const float* __restrict__ Xk, const float* __restrict__ Xv,
    const float* __restrict__ Xq,
    u16* __restrict__ WqT, u16* __restrict__ WkT,
    u16* __restrict__ WvT, u16* __restrict__ WoT,
    u16* __restrict__ Xk16, u16* __restrict__ Xv16, u16* __restrict__ Xq16)
{
  const int bid = blockIdx.x;
  const int tid = threadIdx.x;

  if (bid >= 432) {
    const int i = bid - 432;
    const int t = i / 3072;                       // 0: Xk  1: Xv  2: Xq
    const long e = ((long)(i % 3072) * 256 + tid) * 8;
    const float* src = (t == 0) ? Xk : (t == 1) ? Xv : Xq;
    u16* dst = (t == 0) ? Xk16 : (t == 1) ? Xv16 : Xq16;
    f32x4 a = *(const f32x4*)(&src[e]);
    f32x4 b = *(const f32x4*)(&src[e + 4]);
    u16x8 v;
    #pragma unroll
    for (int j = 0; j < 4; j++) { v[j] = f2h(a[j]); v[4 + j] = f2h(b[j]); }
    *(u16x8*)(&dst[e]) = v;
    return;
  }

  if (bid < 288) {
    __shared__ u16 Lt[96][72];
    const int w = bid / 96;
    const int r = bid % 96;
    const int h = r / 12, dt = r % 12;
    const float* W = (w == 0) ? Wq : (w == 1) ? Wk : Wv;
    u16* T = (w == 0) ? WqT : (w == 1) ? WkT : WvT;
    const float* src = W + (size_t)h * 73728 + (size_t)dt * 64 * 96;
    #pragma unroll
    for (int p = 0; p < 6; p++) {
      const int lin = p * 1024 + tid * 4;
      f32x4 v = *(const f32x4*)(&src[lin]);
      const int d = lin / 96, kk = lin % 96;
      #pragma unroll
      for (int j = 0; j < 4; j++) Lt[kk + j][d] = f2h(v[j]);
    }
    __syncthreads();
    #pragma unroll
    for (int c = 0; c < 3; c++) {
      const int ch = c * 256 + tid;
      const int kk = ch >> 3, dc = ch & 7;
      u16x8 o = *(const u16x8*)(&Lt[kk][dc * 8]);
      *(u16x8*)(&T[(size_t)(h * 96 + kk) * 768 + dt * 64 + dc * 8]) = o;
    }
    return;
  }

  {
    __shared__ u16 Lo[64][72];
    const int i = bid - 288;
    const int kt = i / 12, nt = i % 12;
    const float* src = Wo + (size_t)(kt * 64) * 768 + nt * 64;
    #pragma unroll
    for (int p = 0; p < 4; p++) {
      const int lin = p * 1024 + tid * 4;
      const int kr = lin >> 6, nc = lin & 63;
      f32x4 v = *(const f32x4*)(&src[(size_t)kr * 768 + nc]);
      #pragma unroll
      for (int j = 0; j < 4; j++) Lo[nc + j][kr] = f2h(v[j]);
    }
    __syncthreads();
    #pragma unroll
    for (int c = 0; c < 2; c++) {
      const int ch = c * 256 + tid;
      const int nr = ch >> 3, kc = ch & 7;
      u16x8 o = *(const u16x8*)(&Lo[nr][kc * 8]);
      *(u16x8*)(&WoT[(size_t)(nt * 64 + nr) * 768 + kt * 64 + kc * 8]) = o;
    }
  }
}

// ---------------------------------------------------------------------------
// Batched QKV GEMM (unchanged R7): BM=128 BN=128 BK=32, 2-phase counted-vmcnt.
// ---------------------------------------------------------------------------
#define GK 768

__global__ __launch_bounds__(256) void gemm_qkv(
    const u16* __restrict__ Xq16, const u16* __restrict__ Xk16,
    const u16* __restrict__ Xv16, const u16* __restrict__ WT,
    const float* __restrict__ bq, const float* __restrict__ bk,
    const float* __restrict__ bv,
    u16* __restrict__ Q16, u16* __restrict__ K16, u16* __restrict__ VT)
{
  const int z = blockIdx.z;
  const u16* BT = WT + (size_t)z * 589824;
  const float* bias = (z == 0) ? bq : (z == 1) ? bk : bv;
  const u16* A = (z == 0) ? Xq16 : (z == 1) ? Xk16 : Xv16;

  __shared__ __align__(16) u16 Sb[16384];

  const int tid = threadIdx.x;
  const int wave = tid >> 6;
  const int lane = tid & 63;
  const int quad = lane >> 4;
  const int l16 = lane & 15;
  const int m0 = blockIdx.x * 128;
  const int n0 = blockIdx.y * 128;

  f32x4 acc[2][8];
  #pragma unroll
  for (int i = 0; i < 2; i++)
    #pragma unroll
    for (int j = 0; j < 8; j++) acc[i][j] = (f32x4){0.f, 0.f, 0.f, 0.f};

  const int c0 = tid, c1 = tid + 256;
  const u16* gA0 = A + (size_t)(m0 + (c0 >> 2)) * GK + (c0 & 3) * 8;
  const u16* gA1 = A + (size_t)(m0 + (c1 >> 2)) * GK + (c1 & 3) * 8;
  const u16* gB0 = BT + (size_t)(n0 + (c0 >> 2)) * GK + (c0 & 3) * 8;
  const u16* gB1 = BT + (size_t)(n0 + (c1 >> 2)) * GK + (c1 & 3) * 8;
  const int ld0 = (wave * 64) * 8;
  const int ld1 = (256 + wave * 64) * 8;

#define STAGE(buf, kt) do {                                        \
    const int k0_ = (kt) * 32;                                     \
    u16* dst_ = Sb + (buf) * 8192;                                 \
    gll16(gA0 + k0_, dst_ + ld0);                                  \
    gll16(gA1 + k0_, dst_ + ld1);                                  \
    gll16(gB0 + k0_, dst_ + 4096 + ld0);                           \
    gll16(gB1 + k0_, dst_ + 4096 + ld1);                           \
  } while (0)

  STAGE(0, 0);
  int buf = 0;
  for (int kt = 0; kt < 24; kt++) {
    if (kt + 1 < 24) {
      STAGE(buf ^ 1, kt + 1);
      asm volatile("s_waitcnt vmcnt(4)" ::: "memory");
    } else {
      asm volatile("s_waitcnt vmcnt(0)" ::: "memory");
    }
    __builtin_amdgcn_s_barrier();

    const u16* As = Sb + buf * 8192;
    const u16* Bs = As + 4096;
    h16x8 af[2], bf[8];
    #pragma unroll
    for (int mf = 0; mf < 2; mf++)
      af[mf] = *(const h16x8*)(&As[(wave * 32 + mf * 16 + l16) * 32 + quad * 8]);
    #pragma unroll
    for (int nf = 0; nf < 8; nf++)
      bf[nf] = *(const h16x8*)(&Bs[(nf * 16 + l16) * 32 + quad * 8]);
    #pragma unroll
    for (int mf = 0; mf < 2; mf++)
      #pragma unroll
      for (int nf = 0; nf < 8; nf++)
        acc[mf][nf] = __builtin_amdgcn_mfma_f32_16x16x32_f16(af[mf], bf[nf], acc[mf][nf], 0, 0, 0);

    __builtin_amdgcn_s_barrier();
    buf ^= 1;
  }
#undef STAGE

  if (z == 2) {
    const int b = m0 >> 11, s0 = m0 & 2047;
    u16* Ts = Sb;
    #pragma unroll
    for (int half = 0; half < 2; half++) {
      __syncthreads();
      #pragma unroll
      for (int nf2 = 0; nf2 < 4; nf2++) {
        const int nf = half * 4 + nf2;
        const float bv2 = bias[n0 + nf * 16 + l16];
        #pragma unroll
        for (int mf = 0; mf < 2; mf++)
          #pragma unroll
          for (int r = 0; r < 4; r++)
            Ts[(nf2 * 16 + l16) * 136 + wave * 32 + mf * 16 + quad * 4 + r] =
                f2h(acc[mf][nf][r] + bv2);
      }
      __syncthreads();
      #pragma unroll
      for (int p = 0; p < 4; p++) {
        const int c = p * 256 + tid;
        const int row = c >> 4, col8 = (c & 15) * 8;
        u16x8 o8 = *(const u16x8*)(&Ts[row * 136 + col8]);
        *(u16x8*)(&VT[(size_t)b * 768 * 2048 +
                      (size_t)(n0 + half * 64 + row) * 2048 + s0 + col8]) = o8;
      }
    }
    return;
  }

  u16* Yr = (z == 0) ? Q16 : K16;
  #pragma unroll
  for (int nf = 0; nf < 8; nf++) {
    const int n = n0 + nf * 16 + l16;
    const float bv2 = bias[n];
    #pragma unroll
    for (int mf = 0; mf < 2; mf++) {
      const int m = m0 + wave * 32 + mf * 16 + quad * 4;
      #pragma unroll
      for (int r = 0; r < 4; r++)
        Yr[(size_t)(m + r) * GK + n] = f2h(acc[mf][nf][r] + bv2);
    }
  }
}

// ---------------------------------------------------------------------------
// GEMM_O (unchanged R7).
// ---------------------------------------------------------------------------
__global__ __launch_bounds__(256) void gemm_o(
    const u16* __restrict__ A, const u16* __restrict__ BT,
    const float* __restrict__ bias, float* __restrict__ Y)
{
  __shared__ __align__(16) u16 Sb[16384];

  const int tid = threadIdx.x;
  const int wave = tid >> 6;
  const int lane = tid & 63;
  const int quad = lane >> 4;
  const int l16 = lane & 15;
  const int m0 = blockIdx.x * 128;
  const int n0 = blockIdx.y * 128;

  f32x4 acc[2][8];
  #pragma unroll
  for (int i = 0; i < 2; i++)
    #pragma unroll
    for (int j = 0; j < 8; j++) acc[i][j] = (f32x4){0.f, 0.f, 0.f, 0.f};

  const int c0 = tid, c1 = tid + 256;
  const u16* gA0 = A + (size_t)(m0 + (c0 >> 2)) * GK + (c0 & 3) * 8;
  const u16* gA1 = A + (size_t)(m0 + (c1 >> 2)) * GK + (c1 & 3) * 8;
  const u16* gB0 = BT + (size_t)(n0 + (c0 >> 2)) * GK + (c0 & 3) * 8;
  const u16* gB1 = BT + (size_t)(n0 + (c1 >> 2)) * GK + (c1 & 3) * 8;
  const int ld0 = (wave * 64) * 8;
  const int ld1 = (256 + wave * 64) * 8;

#define STAGE(buf, kt) do {                                        \
    const int k0_ = (kt) * 32;                                     \
    u16* dst_ = Sb + (buf) * 8192;                                 \
    gll16(gA0 + k0_, dst_ + ld0);                                  \
    gll16(gA1 + k0_, dst_ + ld1);                                  \
    gll16(gB0 + k0_, dst_ + 4096 + ld0);                           \
    gll16(gB1 + k0_, dst_ + 4096 + ld1);                           \
  } while (0)

  STAGE(0, 0);
  int buf = 0;
  for (int kt = 0; kt < 24; kt++) {
    if (kt + 1 < 24) {
      STAGE(buf ^ 1, kt + 1);
      asm volatile("s_waitcnt vmcnt(4)" ::: "memory");
    } else {
      asm volatile("s_waitcnt vmcnt(0)" ::: "memory");
    }
    __builtin_amdgcn_s_barrier();

    const u16* As = Sb + buf * 8192;
    const u16* Bs = As + 4096;
    h16x8 af[2], bf[8];
    #pragma unroll
    for (int mf = 0; mf < 2; mf++)
      af[mf] = *(const h16x8*)(&As[(wave * 32 + mf * 16 + l16) * 32 + quad * 8]);
    #pragma unroll
    for (int nf = 0; nf < 8; nf++)
      bf[nf] = *(const h16x8*)(&Bs[(nf * 16 + l16) * 32 + quad * 8]);
    #pragma unroll
    for (int mf = 0; mf < 2; mf++)
      #pragma unroll
      for (int nf = 0; nf < 8; nf++)
        acc[mf][nf] = __builtin_amdgcn_mfma_f32_16x16x32_f16(af[mf], bf[nf], acc[mf][nf], 0, 0, 0);

    __builtin_amdgcn_s_barrier();
    buf ^= 1;
  }
#undef STAGE

  #pragma unroll
  for (int nf = 0; nf < 8; nf++) {
    const int n = n0 + nf * 16 + l16;
    const float bv = bias[n];
    #pragma unroll
    for (int mf = 0; mf < 2; mf++) {
      const int m = m0 + wave * 32 + mf * 16 + quad * 4;
      #pragma unroll
      for (int r = 0; r < 4; r++)
        Y[(size_t)(m + r) * GK + n] = acc[mf][nf][r] + bv;
    }
  }
}

// ---------------------------------------------------------------------------
// Flash attention, in-block KV-split. 512 thr / 8 waves; group g = wave>>2
// handles KV tiles [g*16, g*16+16); each wave owns 32 q-rows (2 mf groups).
// Single K/V buffer per group (reg-prefetch, write-late); half-k P buffer;
// flash-combine merge epilogue via LDS scratch. LDS 74.8KB -> 2 blocks/CU.
// defer-max (T13); setprio (T5).
// ---------------------------------------------------------------------------
#define SEQ 2048
#define LQK 104
#define LVT 72
#define LPS 40

__global__ __launch_bounds__(512, 4) void attn_kernel(
    const u16* __restrict__ Q, const u16* __restrict__ K,
    const u16* __restrict__ VT, u16* __restrict__ O)
{
  // Ks: 2 x 64 x LQK = 13312 u16 | Vt: 2 x 96 x LVT = 13824 | Ps: 8 x 32 x LPS = 10240
  __shared__ __align__(16) u16 SMEM[13312 + 13824 + 10240];
  u16* Ksb = SMEM;
  u16* Vtb = SMEM + 13312;
  u16* Psb = SMEM + 27136;

  const int tid = threadIdx.x;
  const int wave = tid >> 6;
  const int lane = tid & 63;
  const int quad = lane >> 4;
  const int l16 = lane & 15;
  const int g = wave >> 2;          // KV group
  const int w4 = wave & 3;          // q-sub within block
  const int tg = tid & 255;         // thread within group

  const int bh = blockIdx.y;
  const int b = bh >> 3, h = bh & 7;
  const int q0 = blockIdx.x * 128;
  const int qbase = q0 + w4 * 32;

  const size_t batch_off = (size_t)b * SEQ * 768;
  const u16* Kg = K + batch_off + h * 96;
  const u16* Vg = VT + (size_t)b * 768 * 2048 + (size_t)(h * 96) * 2048;

  // Q fragments: 2 mf groups x 3 ks
  h16x8 qf[2][3];
  #pragma unroll
  for (int mf = 0; mf < 2; mf++) {
    const u16* Qrow = Q + batch_off +
        (size_t)(qbase + mf * 16 + l16) * 768 + h * 96 + quad * 8;
    #pragma unroll
    for (int ks = 0; ks < 3; ks++) qf[mf][ks] = *(const h16x8*)(&Qrow[ks * 32]);
  }

  // staging geometry: K 64x96 = 768 chunks, V 96x64 = 768 chunks; 3 each/thread
  int kof[3], kgf[3], vof[3], vgf[3];
  #pragma unroll
  for (int j = 0; j < 3; j++) {
    const int c = tg + j * 256;
    const int kr = c / 12, kc = (c % 12) * 8;
    const int vr = c >> 3, vc = (c & 7) * 8;
    kof[j] = kr * LQK + kc;  kgf[j] = kr * 768 + kc;
    vof[j] = vr * LVT + vc;  vgf[j] = vr * 2048 + vc;
  }
  u16* Ksg = Ksb + g * 6656;
  u16* Vtg = Vtb + g * 6912;

  f32x4 o[2][6];
  #pragma unroll
  for (int mf = 0; mf < 2; mf++)
    #pragma unroll
    for (int i = 0; i < 6; i++) o[mf][i] = (f32x4){0.f, 0.f, 0.f, 0.f};
  float m_raw[2] = {-1e30f, -1e30f};
  float lrow[2] = {0.f, 0.f};
  const float sc = 0.14724498f;      // log2(e)/sqrt(96)

  u16* Pw = Psb + wave * 32 * LPS;

  const int t0 = g * 16;
  u16x8 kR[3], vR[3];

#define LOADT(t) do {                                                   \
    const u16* Kt_ = Kg + (size_t)(t) * 64 * 768;                       \
    const u16* Vt_ = Vg + (size_t)(t) * 64;                             \
    _Pragma("unroll")                                                   \
    for (int j = 0; j < 3; j++) {                                       \
      kR[j] = *(const u16x8*)(&Kt_[kgf[j]]);                            \
      vR[j] = *(const u16x8*)(&Vt_[vgf[j]]);                            \
    }                                                                   \
  } while (0)
#define WRITET() do {                                                   \
    _Pragma("unroll")                                                   \
    for (int j = 0; j < 3; j++) {                                       \
      *(u16x8*)(&Ksg[kof[j]]) = kR[j];                                  \
      *(u16x8*)(&Vtg[vof[j]]) = vR[j];                                  \
    }                                                                   \
  } while (0)

  // prolog: stage tile t0; preload t0+1
  LOADT(t0);
  WRITET();
  LOADT(t0 + 1);
  __syncthreads();

  for (int i = 0; i < 16; i++) {
    // ---- QK^T: K fragment read once, feeds both mf groups ----
    f32x4 s[2][4];
    #pragma unroll
    for (int mf = 0; mf < 2; mf++)
      #pragma unroll
      for (int kf = 0; kf < 4; kf++) s[mf][kf] = (f32x4){0.f, 0.f, 0.f, 0.f};
    __builtin_amdgcn_s_setprio(1);
    #pragma unroll
    for (int ks = 0; ks < 3; ks++) {
      #pragma unroll
      for (int kf = 0; kf < 4; kf++) {
        h16x8 a = *(const h16x8*)(&Ksg[(kf * 16 + l16) * LQK + ks * 32 + quad * 8]);
        s[0][kf] = __builtin_amdgcn_mfma_f32_16x16x32_f16(a, qf[0][ks], s[0][kf], 0, 0, 0);
        s[1][kf] = __builtin_amdgcn_mfma_f32_16x16x32_f16(a, qf[1][ks], s[1][kf], 0, 0, 0);
      }
    }
    __builtin_amdgcn_s_setprio(0);

    // ---- online softmax per mf (defer-max T13) ----
    #pragma unroll
    for (int mf = 0; mf < 2; mf++) {
      float mx = s[mf][0][0];
      #pragma unroll
      for (int kf = 0; kf < 4; kf++)
        #pragma unroll
        for (int r = 0; r < 4; r++) mx = fmaxf(mx, s[mf][kf][r]);
      mx = fmaxf(mx, __shfl_xor(mx, 16));
      mx = fmaxf(mx, __shfl_xor(mx, 32));
      if (__any(mx > m_raw[mf] + 54.0f)) {
        const float mnew = fmaxf(m_raw[mf], mx);
        const float alpha = exp2f(sc * (m_raw[mf] - mnew));  // 0 on first tile
        lrow[mf] *= alpha;
        #pragma unroll
        for (int nfo = 0; nfo < 6; nfo++)
          #pragma unroll
          for (int r = 0; r < 4; r++) o[mf][nfo][r] *= alpha;
        m_raw[mf] = mnew;
      }
      const float c0 = sc * m_raw[mf];
      float ps = 0.f;
      #pragma unroll
      for (int kf = 0; kf < 4; kf++)
        #pragma unroll
        for (int r = 0; r < 4; r++) {
          float p = exp2f(fmaf(s[mf][kf][r], sc, -c0));
          s[mf][kf][r] = p;
          ps += p;
        }
      lrow[mf] += ps;   // quad-partial
    }

    // ---- PV in 2 k-halves (half-k P buffer, wave-local reuse) ----
    #pragma unroll
    for (int hk = 0; hk < 2; hk++) {
      #pragma unroll
      for (int mf = 0; mf < 2; mf++)
        #pragma unroll
        for (int kf2 = 0; kf2 < 2; kf2++) {
          const int kf = hk * 2 + kf2;
          fp16x2 a2 = __builtin_amdgcn_cvt_pkrtz(s[mf][kf][0], s[mf][kf][1]);
          fp16x2 b2 = __builtin_amdgcn_cvt_pkrtz(s[mf][kf][2], s[mf][kf][3]);
          fp16x4 w4p; w4p[0] = a2[0]; w4p[1] = a2[1]; w4p[2] = b2[0]; w4p[3] = b2[1];
          *(fp16x4*)(&Pw[(mf * 16 + l16) * LPS + kf2 * 16 + quad * 4]) = w4p;
        }
      h16x8 pf0 = *(const h16x8*)(&Pw[l16 * LPS + quad * 8]);
      h16x8 pf1 = *(const h16x8*)(&Pw[(16 + l16) * LPS + quad * 8]);
      __builtin_amdgcn_s_setprio(1);
      #pragma unroll
      for (int nfo = 0; nfo < 6; nfo++) {
        h16x8 vfr = *(const h16x8*)(&Vtg[(nfo * 16 + l16) * LVT + hk * 32 + quad * 8]);
        o[0][nfo] = __builtin_amdgcn_mfma_f32_16x16x32_f16(vfr, pf0, o[0][nfo], 0, 0, 0);
        o[1][nfo] = __builtin_amdgcn_mfma_f32_16x16x32_f16(vfr, pf1, o[1][nfo], 0, 0, 0);
      }
      __builtin_amdgcn_s_setprio(0);
    }

    // ---- single-buffer staging: write tile i+1, preload i+2 ----
    if (i + 1 < 16) {
      __syncthreads();                 // group done reading tile i
      WRITET();
      if (i + 2 < 16) LOADT(t0 + i + 2);
      __syncthreads();                 // tile i+1 ready
    }
  }
#undef LOADT
#undef WRITET

  // ---- flash-combine merge of the two KV-group partials ----
  __syncthreads();                     // everyone done with Ks/Vt
  #pragma unroll
  for (int mf = 0; mf < 2; mf++) {
    lrow[mf] += __shfl_xor(lrow[mf], 16);
    lrow[mf] += __shfl_xor(lrow[mf], 32);
  }
  float* Ms = (float*)SMEM;            // 4 slots x 32 rows x 96 f32 = 48KB
  float* MLs = (float*)Psb;            // 4 slots x 32 rows x 2 f32

  if (g == 1) {
    float* os = Ms + w4 * (32 * 96);
    #pragma unroll
    for (int mf = 0; mf < 2; mf++) {
      #pragma unroll
      for (int nfo = 0; nfo < 6; nfo++)
        *(f32x4*)(&os[(mf * 16 + l16) * 96 + nfo * 16 + quad * 4]) = o[mf][nfo];
      if (quad == 0) {
        MLs[(w4 * 32 + mf * 16 + l16) * 2 + 0] = m_raw[mf];
        MLs[(w4 * 32 + mf * 16 + l16) * 2 + 1] = lrow[mf];
      }
    }
  }
  __syncthreads();
  if (g == 0) {
    float* os = Ms + w4 * (32 * 96);
    #pragma unroll
    for (int mf = 0; mf < 2; mf++) {
      const float m1 = MLs[(w4 * 32 + mf * 16 + l16) * 2 + 0];
      const float l1 = MLs[(w4 * 32 + mf * 16 + l16) * 2 + 1];
      const float mm = fmaxf(m_raw[mf], m1);
      const float e0 = exp2f(sc * (m_raw[mf] - mm));
      const float e1 = exp2f(sc * (m1 - mm));
      const float inv = 1.0f / (e0 * lrow[mf] + e1 * l1);
      const float a0 = e0 * inv, a1 = e1 * inv;
      u16* Ob = O + batch_off + (size_t)(qbase + mf * 16 + l16) * 768 + h * 96;
      #pragma unroll
      for (int nfo = 0; nfo < 6; nfo++) {
        f32x4 o1 = *(const f32x4*)(&os[(mf * 16 + l16) * 96 + nfo * 16 + quad * 4]);
        float v0 = a0 * o[mf][nfo][0] + a1 * o1[0];
        float v1 = a0 * o[mf][nfo][1] + a1 * o1[1];
        float v2 = a0 * o[mf][nfo][2] + a1 * o1[2];
        float v3 = a0 * o[mf][nfo][3] + a1 * o1[3];
        fp16x2 lo = __builtin_amdgcn_cvt_pkrtz(v0, v1);
        fp16x2 hi = __builtin_amdgcn_cvt_pkrtz(v2, v3);
        *(fp16x2*)(&Ob[nfo * 16 + quad * 4]) = lo;
        *(fp16x2*)(&Ob[nfo * 16 + quad * 4 + 2]) = hi;
      }
    }
  }
}

// ---------------------------------------------------------------------------
extern "C" void kernel_launch(void* const* d_in, const int* in_sizes, int n_in,
                              void* d_out, int out_size, void* d_ws, size_t ws_size,
                              hipStream_t stream) {
  const float* Xq = (const float*)d_in[0];
  const float* Xk = (const float*)d_in[1];
  const float* Xv = (const float*)d_in[2];
  const float* Wq = (const float*)d_in[3];
  const float* bq = (const float*)d_in[4];
  const float* Wk = (const float*)d_in[5];
  const float* bk = (const float*)d_in[6];
  const float* Wv = (const float*)d_in[7];
  const float* bv = (const float*)d_in[8];
  const float* Wo = (const float*)d_in[9];
  const float* bo = (const float*)d_in[10];

  u16* wsu = (u16*)d_ws;
  u16* WT   = wsu;                    // WqT | WkT | WvT, 589824 each
  u16* WoT  = wsu + 3 * 589824;
  u16* Q16  = wsu + 4 * 589824;       // 12.6 MB
  u16* Xk16 = Q16 + 6291456;          // 12.6 MB
  u16* Xv16 = Xk16 + 6291456;         // 12.6 MB
  u16* Xq16 = Xv16 + 6291456;         // 12.6 MB (total 55.05 MB)

  u16* outu = (u16*)d_out;
  u16* VTb = outu;                   // V^T f16 [4][768][2048]
  u16* K16 = outu + 6291456;         // K f16 rowmajor

  u16* A16 = Xk16;                   // attn out overlays Xk16 (dead after
                                     // gemm_qkv) -- d_in never written.

  prep_kernel<<<9648, 256, 0, stream>>>(
      Wq, Wk, Wv, Wo, Xk, Xv, Xq,
      WT, WT + 589824, WT + 2 * 589824, WoT, Xk16, Xv16, Xq16);
  gemm_qkv<<<dim3(64, 6, 3), 256, 0, stream>>>(
      Xq16, Xk16, Xv16, WT, bq, bk, bv, Q16, K16, VTb);
  attn_kernel<<<dim3(16, 32), 512, 0, stream>>>(Q16, K16, VTb, A16);
  gemm_o<<<dim3(64, 6), 256, 0, stream>>>(A16, WoT, bo, (float*)d_out);
}

// Round 9
// 355.726 us; speedup vs baseline: 1.2299x; 1.2299x over previous
//
#include <hip/hip_runtime.h>

// Multi-head attention, B=4 S=2048 D=768 H=8 DH=96. FP32 I/O, f16 MFMA compute.
// R17: R16's in-block KV-split attn with SPILL FIX: staging prefetch (kR/vR)
//      rescheduled so it is never live during QK^T (the R16 peak was
//      o48+qf24+s32+kRvR24 > 128 -> in-loop scratch spill, 423MB writes).
//      New order: QK^T -> softmax -> P/PV half0 -> P half1 -> LOADT(i+1) ->
//      PV half1 -> sync/WRITET/sync. Peak live ~110 VGPR < 128 cap.
//      Waves 0-3 do KV tiles 0-15, waves 4-7 do 16-31, same 128 q-rows
//      (32 q/wave, 2 mf groups -> each K/V fragment feeds 2 MFMAs).
//      Grid (16,32), LDS 74.8KB, 2 blocks/CU, 16 waves/CU.
//      GEMMs/prep unchanged from R7 (clean A/B).
// Buffers: ws = [WqT|WkT|WvT|WoT (4.7MB) | Q16 | Xk16 | Xv16 | Xq16] = 55.05MB
//          A16 overlays Xk16 after gemm_qkv (d_in never written).
//          d_out = [VT (12.6MB) | K16 (12.6MB)] f16 until GEMM_O overwrites.

typedef unsigned short u16;
typedef _Float16 h16;
typedef h16 h16x8 __attribute__((ext_vector_type(8)));
typedef __fp16 fp16x2 __attribute__((ext_vector_type(2)));
typedef __fp16 fp16x4 __attribute__((ext_vector_type(4)));
typedef unsigned short u16x8 __attribute__((ext_vector_type(8)));
typedef unsigned short u16x4 __attribute__((ext_vector_type(4)));
typedef float f32x4 __attribute__((ext_vector_type(4)));

__device__ __forceinline__ u16 f2h(float f) {
  union { h16 h; u16 u; } c; c.h = (h16)f; return c.u;
}

__device__ __forceinline__ void gll16(const void* g, void* l) {
  __builtin_amdgcn_global_load_lds(
      (const __attribute__((address_space(1))) void*)g,
      (__attribute__((address_space(3))) void*)l, 16, 0, 0);
}

// ---------------------------------------------------------------------------
// prep: LDS-tiled weight transposes + X f16 conversions (unchanged).
// ---------------------------------------------------------------------------
__global__ __launch_bounds__(256) void prep_kernel(
    const float* __restrict__ Wq, const float* __restrict__ Wk,
    const float* __restrict__ Wv, const float* __restrict__ Wo,
    const float* __restrict__ Xk, const float* __restrict__ Xv,
    const float* __restrict__ Xq,
    u16* __restrict__ WqT, u16* __restrict__ WkT,
    u16* __restrict__ WvT, u16* __restrict__ WoT,
    u16* __restrict__ Xk16, u16* __restrict__ Xv16, u16* __restrict__ Xq16)
{
  const int bid = blockIdx.x;
  const int tid = threadIdx.x;

  if (bid >= 432) {
    const int i = bid - 432;
    const int t = i / 3072;                       // 0: Xk  1: Xv  2: Xq
    const long e = ((long)(i % 3072) * 256 + tid) * 8;
    const float* src = (t == 0) ? Xk : (t == 1) ? Xv : Xq;
    u16* dst = (t == 0) ? Xk16 : (t == 1) ? Xv16 : Xq16;
    f32x4 a = *(const f32x4*)(&src[e]);
    f32x4 b = *(const f32x4*)(&src[e + 4]);
    u16x8 v;
    #pragma unroll
    for (int j = 0; j < 4; j++) { v[j] = f2h(a[j]); v[4 + j] = f2h(b[j]); }
    *(u16x8*)(&dst[e]) = v;
    return;
  }

  if (bid < 288) {
    __shared__ u16 Lt[96][72];
    const int w = bid / 96;
    const int r = bid % 96;
    const int h = r / 12, dt = r % 12;
    const float* W = (w == 0) ? Wq : (w == 1) ? Wk : Wv;
    u16* T = (w == 0) ? WqT : (w == 1) ? WkT : WvT;
    const float* src = W + (size_t)h * 73728 + (size_t)dt * 64 * 96;
    #pragma unroll
    for (int p = 0; p < 6; p++) {
      const int lin = p * 1024 + tid * 4;
      f32x4 v = *(const f32x4*)(&src[lin]);
      const int d = lin / 96, kk = lin % 96;
      #pragma unroll
      for (int j = 0; j < 4; j++) Lt[kk + j][d] = f2h(v[j]);
    }
    __syncthreads();
    #pragma unroll
    for (int c = 0; c < 3; c++) {
      const int ch = c * 256 + tid;
      const int kk = ch >> 3, dc = ch & 7;
      u16x8 o = *(const u16x8*)(&Lt[kk][dc * 8]);
      *(u16x8*)(&T[(size_t)(h * 96 + kk) * 768 + dt * 64 + dc * 8]) = o;
    }
    return;
  }

  {
    __shared__ u16 Lo[64][72];
    const int i = bid - 288;
    const int kt = i / 12, nt = i % 12;
    const float* src = Wo + (size_t)(kt * 64) * 768 + nt * 64;
    #pragma unroll
    for (int p = 0; p < 4; p++) {
      const int lin = p * 1024 + tid * 4;
      const int kr = lin >> 6, nc = lin & 63;
      f32x4 v = *(const f32x4*)(&src[(size_t)kr * 768 + nc]);
      #pragma unroll
      for (int j = 0; j < 4; j++) Lo[nc + j][kr] = f2h(v[j]);
    }
    __syncthreads();
    #pragma unroll
    for (int c = 0; c < 2; c++) {
      const int ch = c * 256 + tid;
      const int nr = ch >> 3, kc = ch & 7;
      u16x8 o = *(const u16x8*)(&Lo[nr][kc * 8]);
      *(u16x8*)(&WoT[(size_t)(nt * 64 + nr) * 768 + kt * 64 + kc * 8]) = o;
    }
  }
}

// ---------------------------------------------------------------------------
// Batched QKV GEMM (unchanged R7): BM=128 BN=128 BK=32, 2-phase counted-vmcnt.
// ---------------------------------------------------------------------------
#define GK 768

__global__ __launch_bounds__(256) void gemm_qkv(
    const u16* __restrict__ Xq16, const u16* __restrict__ Xk16,
    const u16* __restrict__ Xv16, const u16* __restrict__ WT,
    const float* __restrict__ bq, const float* __restrict__ bk,
    const float* __restrict__ bv,
    u16* __restrict__ Q16, u16* __restrict__ K16, u16* __restrict__ VT)
{
  const int z = blockIdx.z;
  const u16* BT = WT + (size_t)z * 589824;
  const float* bias = (z == 0) ? bq : (z == 1) ? bk : bv;
  const u16* A = (z == 0) ? Xq16 : (z == 1) ? Xk16 : Xv16;

  __shared__ __align__(16) u16 Sb[16384];

  const int tid = threadIdx.x;
  const int wave = tid >> 6;
  const int lane = tid & 63;
  const int quad = lane >> 4;
  const int l16 = lane & 15;
  const int m0 = blockIdx.x * 128;
  const int n0 = blockIdx.y * 128;

  f32x4 acc[2][8];
  #pragma unroll
  for (int i = 0; i < 2; i++)
    #pragma unroll
    for (int j = 0; j < 8; j++) acc[i][j] = (f32x4){0.f, 0.f, 0.f, 0.f};

  const int c0 = tid, c1 = tid + 256;
  const u16* gA0 = A + (size_t)(m0 + (c0 >> 2)) * GK + (c0 & 3) * 8;
  const u16* gA1 = A + (size_t)(m0 + (c1 >> 2)) * GK + (c1 & 3) * 8;
  const u16* gB0 = BT + (size_t)(n0 + (c0 >> 2)) * GK + (c0 & 3) * 8;
  const u16* gB1 = BT + (size_t)(n0 + (c1 >> 2)) * GK + (c1 & 3) * 8;
  const int ld0 = (wave * 64) * 8;
  const int ld1 = (256 + wave * 64) * 8;

#define STAGE(buf, kt) do {                                        \
    const int k0_ = (kt) * 32;                                     \
    u16* dst_ = Sb + (buf) * 8192;                                 \
    gll16(gA0 + k0_, dst_ + ld0);                                  \
    gll16(gA1 + k0_, dst_ + ld1);                                  \
    gll16(gB0 + k0_, dst_ + 4096 + ld0);                           \
    gll16(gB1 + k0_, dst_ + 4096 + ld1);                           \
  } while (0)

  STAGE(0, 0);
  int buf = 0;
  for (int kt = 0; kt < 24; kt++) {
    if (kt + 1 < 24) {
      STAGE(buf ^ 1, kt + 1);
      asm volatile("s_waitcnt vmcnt(4)" ::: "memory");
    } else {
      asm volatile("s_waitcnt vmcnt(0)" ::: "memory");
    }
    __builtin_amdgcn_s_barrier();

    const u16* As = Sb + buf * 8192;
    const u16* Bs = As + 4096;
    h16x8 af[2], bf[8];
    #pragma unroll
    for (int mf = 0; mf < 2; mf++)
      af[mf] = *(const h16x8*)(&As[(wave * 32 + mf * 16 + l16) * 32 + quad * 8]);
    #pragma unroll
    for (int nf = 0; nf < 8; nf++)
      bf[nf] = *(const h16x8*)(&Bs[(nf * 16 + l16) * 32 + quad * 8]);
    #pragma unroll
    for (int mf = 0; mf < 2; mf++)
      #pragma unroll
      for (int nf = 0; nf < 8; nf++)
        acc[mf][nf] = __builtin_amdgcn_mfma_f32_16x16x32_f16(af[mf], bf[nf], acc[mf][nf], 0, 0, 0);

    __builtin_amdgcn_s_barrier();
    buf ^= 1;
  }
#undef STAGE

  if (z == 2) {
    const int b = m0 >> 11, s0 = m0 & 2047;
    u16* Ts = Sb;
    #pragma unroll
    for (int half = 0; half < 2; half++) {
      __syncthreads();
      #pragma unroll
      for (int nf2 = 0; nf2 < 4; nf2++) {
        const int nf = half * 4 + nf2;
        const float bv2 = bias[n0 + nf * 16 + l16];
        #pragma unroll
        for (int mf = 0; mf < 2; mf++)
          #pragma unroll
          for (int r = 0; r < 4; r++)
            Ts[(nf2 * 16 + l16) * 136 + wave * 32 + mf * 16 + quad * 4 + r] =
                f2h(acc[mf][nf][r] + bv2);
      }
      __syncthreads();
      #pragma unroll
      for (int p = 0; p < 4; p++) {
        const int c = p * 256 + tid;
        const int row = c >> 4, col8 = (c & 15) * 8;
        u16x8 o8 = *(const u16x8*)(&Ts[row * 136 + col8]);
        *(u16x8*)(&VT[(size_t)b * 768 * 2048 +
                      (size_t)(n0 + half * 64 + row) * 2048 + s0 + col8]) = o8;
      }
    }
    return;
  }

  u16* Yr = (z == 0) ? Q16 : K16;
  #pragma unroll
  for (int nf = 0; nf < 8; nf++) {
    const int n = n0 + nf * 16 + l16;
    const float bv2 = bias[n];
    #pragma unroll
    for (int mf = 0; mf < 2; mf++) {
      const int m = m0 + wave * 32 + mf * 16 + quad * 4;
      #pragma unroll
      for (int r = 0; r < 4; r++)
        Yr[(size_t)(m + r) * GK + n] = f2h(acc[mf][nf][r] + bv2);
    }
  }
}

// ---------------------------------------------------------------------------
// GEMM_O (unchanged R7).
// ---------------------------------------------------------------------------
__global__ __launch_bounds__(256) void gemm_o(
    const u16* __restrict__ A, const u16* __restrict__ BT,
    const float* __restrict__ bias, float* __restrict__ Y)
{
  __shared__ __align__(16) u16 Sb[16384];

  const int tid = threadIdx.x;
  const int wave = tid >> 6;
  const int lane = tid & 63;
  const int quad = lane >> 4;
  const int l16 = lane & 15;
  const int m0 = blockIdx.x * 128;
  const int n0 = blockIdx.y * 128;

  f32x4 acc[2][8];
  #pragma unroll
  for (int i = 0; i < 2; i++)
    #pragma unroll
    for (int j = 0; j < 8; j++) acc[i][j] = (f32x4){0.f, 0.f, 0.f, 0.f};

  const int c0 = tid, c1 = tid + 256;
  const u16* gA0 = A + (size_t)(m0 + (c0 >> 2)) * GK + (c0 & 3) * 8;
  const u16* gA1 = A + (size_t)(m0 + (c1 >> 2)) * GK + (c1 & 3) * 8;
  const u16* gB0 = BT + (size_t)(n0 + (c0 >> 2)) * GK + (c0 & 3) * 8;
  const u16* gB1 = BT + (size_t)(n0 + (c1 >> 2)) * GK + (c1 & 3) * 8;
  const int ld0 = (wave * 64) * 8;
  const int ld1 = (256 + wave * 64) * 8;

#define STAGE(buf, kt) do {                                        \
    const int k0_ = (kt) * 32;                                     \
    u16* dst_ = Sb + (buf) * 8192;                                 \
    gll16(gA0 + k0_, dst_ + ld0);                                  \
    gll16(gA1 + k0_, dst_ + ld1);                                  \
    gll16(gB0 + k0_, dst_ + 4096 + ld0);                           \
    gll16(gB1 + k0_, dst_ + 4096 + ld1);                           \
  } while (0)

  STAGE(0, 0);
  int buf = 0;
  for (int kt = 0; kt < 24; kt++) {
    if (kt + 1 < 24) {
      STAGE(buf ^ 1, kt + 1);
      asm volatile("s_waitcnt vmcnt(4)" ::: "memory");
    } else {
      asm volatile("s_waitcnt vmcnt(0)" ::: "memory");
    }
    __builtin_amdgcn_s_barrier();

    const u16* As = Sb + buf * 8192;
    const u16* Bs = As + 4096;
    h16x8 af[2], bf[8];
    #pragma unroll
    for (int mf = 0; mf < 2; mf++)
      af[mf] = *(const h16x8*)(&As[(wave * 32 + mf * 16 + l16) * 32 + quad * 8]);
    #pragma unroll
    for (int nf = 0; nf < 8; nf++)
      bf[nf] = *(const h16x8*)(&Bs[(nf * 16 + l16) * 32 + quad * 8]);
    #pragma unroll
    for (int mf = 0; mf < 2; mf++)
      #pragma unroll
      for (int nf = 0; nf < 8; nf++)
        acc[mf][nf] = __builtin_amdgcn_mfma_f32_16x16x32_f16(af[mf], bf[nf], acc[mf][nf], 0, 0, 0);

    __builtin_amdgcn_s_barrier();
    buf ^= 1;
  }
#undef STAGE

  #pragma unroll
  for (int nf = 0; nf < 8; nf++) {
    const int n = n0 + nf * 16 + l16;
    const float bv = bias[n];
    #pragma unroll
    for (int mf = 0; mf < 2; mf++) {
      const int m = m0 + wave * 32 + mf * 16 + quad * 4;
      #pragma unroll
      for (int r = 0; r < 4; r++)
        Y[(size_t)(m + r) * GK + n] = acc[mf][nf][r] + bv;
    }
  }
}

// ---------------------------------------------------------------------------
// Flash attention, in-block KV-split with pressure-shaped staging.
// 512 thr / 8 waves; group g = wave>>2 handles KV tiles [g*16, g*16+16);
// each wave owns 32 q-rows (2 mf groups). LOADT issued after P-half1 write
// (s dead) so kR/vR never coexist with s at peak. Half-k P buffer.
// Flash-combine merge epilogue via LDS scratch. LDS 74.8KB -> 2 blocks/CU.
// ---------------------------------------------------------------------------
#define SEQ 2048
#define LQK 104
#define LVT 72
#define LPS 40

__global__ __launch_bounds__(512, 4) void attn_kernel(
    const u16* __restrict__ Q, const u16* __restrict__ K,
    const u16* __restrict__ VT, u16* __restrict__ O)
{
  // Ks: 2 x 64 x LQK = 13312 u16 | Vt: 2 x 96 x LVT = 13824 | Ps: 8 x 32 x LPS = 10240
  __shared__ __align__(16) u16 SMEM[13312 + 13824 + 10240];
  u16* Ksb = SMEM;
  u16* Vtb = SMEM + 13312;
  u16* Psb = SMEM + 27136;

  const int tid = threadIdx.x;
  const int wave = tid >> 6;
  const int lane = tid & 63;
  const int quad = lane >> 4;
  const int l16 = lane & 15;
  const int g = wave >> 2;          // KV group
  const int w4 = wave & 3;          // q-sub within block
  const int tg = tid & 255;         // thread within group

  const int bh = blockIdx.y;
  const int b = bh >> 3, h = bh & 7;
  const int q0 = blockIdx.x * 128;
  const int qbase = q0 + w4 * 32;

  const size_t batch_off = (size_t)b * SEQ * 768;
  const u16* Kg = K + batch_off + h * 96;
  const u16* Vg = VT + (size_t)b * 768 * 2048 + (size_t)(h * 96) * 2048;

  h16x8 qf[2][3];
  #pragma unroll
  for (int mf = 0; mf < 2; mf++) {
    const u16* Qrow = Q + batch_off +
        (size_t)(qbase + mf * 16 + l16) * 768 + h * 96 + quad * 8;
    #pragma unroll
    for (int ks = 0; ks < 3; ks++) qf[mf][ks] = *(const h16x8*)(&Qrow[ks * 32]);
  }

  int kof[3], kgf[3], vof[3], vgf[3];
  #pragma unroll
  for (int j = 0; j < 3; j++) {
    const int c = tg + j * 256;
    const int kr = c / 12, kc = (c % 12) * 8;
    const int vr = c >> 3, vc = (c & 7) * 8;
    kof[j] = kr * LQK + kc;  kgf[j] = kr * 768 + kc;
    vof[j] = vr * LVT + vc;  vgf[j] = vr * 2048 + vc;
  }
  u16* Ksg = Ksb + g * 6656;
  u16* Vtg = Vtb + g * 6912;

  f32x4 o[2][6];
  #pragma unroll
  for (int mf = 0; mf < 2; mf++)
    #pragma unroll
    for (int i = 0; i < 6; i++) o[mf][i] = (f32x4){0.f, 0.f, 0.f, 0.f};
  float m_raw[2] = {-1e30f, -1e30f};
  float lrow[2] = {0.f, 0.f};
  const float sc = 0.14724498f;      // log2(e)/sqrt(96)

  u16* Pw = Psb + wave * 32 * LPS;

  const int t0 = g * 16;
  u16x8 kR[3], vR[3];

#define LOADT(t) do {                                                   \
    const u16* Kt_ = Kg + (size_t)(t) * 64 * 768;                       \
    const u16* Vt_ = Vg + (size_t)(t) * 64;                             \
    _Pragma("unroll")                                                   \
    for (int j = 0; j < 3; j++) {                                       \
      kR[j] = *(const u16x8*)(&Kt_[kgf[j]]);                            \
      vR[j] = *(const u16x8*)(&Vt_[vgf[j]]);                            \
    }                                                                   \
  } while (0)
#define WRITET() do {                                                   \
    _Pragma("unroll")                                                   \
    for (int j = 0; j < 3; j++) {                                       \
      *(u16x8*)(&Ksg[kof[j]]) = kR[j];                                  \
      *(u16x8*)(&Vtg[vof[j]]) = vR[j];                                  \
    }                                                                   \
  } while (0)

  // prolog: stage tile t0 only (no deep prefetch -> low pressure in QK^T)
  LOADT(t0);
  WRITET();
  __syncthreads();

  for (int i = 0; i < 16; i++) {
    // ---- QK^T: K fragment read once, feeds both mf groups ----
    // peak live here: o(48) + qf(24) + s(32) ~ 104
    f32x4 s[2][4];
    #pragma unroll
    for (int mf = 0; mf < 2; mf++)
      #pragma unroll
      for (int kf = 0; kf < 4; kf++) s[mf][kf] = (f32x4){0.f, 0.f, 0.f, 0.f};
    __builtin_amdgcn_s_setprio(1);
    #pragma unroll
    for (int ks = 0; ks < 3; ks++) {
      #pragma unroll
      for (int kf = 0; kf < 4; kf++) {
        h16x8 a = *(const h16x8*)(&Ksg[(kf * 16 + l16) * LQK + ks * 32 + quad * 8]);
        s[0][kf] = __builtin_amdgcn_mfma_f32_16x16x32_f16(a, qf[0][ks], s[0][kf], 0, 0, 0);
        s[1][kf] = __builtin_amdgcn_mfma_f32_16x16x32_f16(a, qf[1][ks], s[1][kf], 0, 0, 0);
      }
    }
    __builtin_amdgcn_s_setprio(0);

    // ---- online softmax per mf (defer-max T13) ----
    #pragma unroll
    for (int mf = 0; mf < 2; mf++) {
      float mx = s[mf][0][0];
      #pragma unroll
      for (int kf = 0; kf < 4; kf++)
        #pragma unroll
        for (int r = 0; r < 4; r++) mx = fmaxf(mx, s[mf][kf][r]);
      mx = fmaxf(mx, __shfl_xor(mx, 16));
      mx = fmaxf(mx, __shfl_xor(mx, 32));
      if (__any(mx > m_raw[mf] + 54.0f)) {
        const float mnew = fmaxf(m_raw[mf], mx);
        const float alpha = exp2f(sc * (m_raw[mf] - mnew));  // 0 on first tile
        lrow[mf] *= alpha;
        #pragma unroll
        for (int nfo = 0; nfo < 6; nfo++)
          #pragma unroll
          for (int r = 0; r < 4; r++) o[mf][nfo][r] *= alpha;
        m_raw[mf] = mnew;
      }
      const float c0 = sc * m_raw[mf];
      float ps = 0.f;
      #pragma unroll
      for (int kf = 0; kf < 4; kf++)
        #pragma unroll
        for (int r = 0; r < 4; r++) {
          float p = exp2f(fmaf(s[mf][kf][r], sc, -c0));
          s[mf][kf][r] = p;
          ps += p;
        }
      lrow[mf] += ps;   // quad-partial
    }

    // ---- P half0 write (kf 0,1) + PV half0 ----
    #pragma unroll
    for (int mf = 0; mf < 2; mf++)
      #pragma unroll
      for (int kf2 = 0; kf2 < 2; kf2++) {
        fp16x2 a2 = __builtin_amdgcn_cvt_pkrtz(s[mf][kf2][0], s[mf][kf2][1]);
        fp16x2 b2 = __builtin_amdgcn_cvt_pkrtz(s[mf][kf2][2], s[mf][kf2][3]);
        fp16x4 w4p; w4p[0] = a2[0]; w4p[1] = a2[1]; w4p[2] = b2[0]; w4p[3] = b2[1];
        *(fp16x4*)(&Pw[(mf * 16 + l16) * LPS + kf2 * 16 + quad * 4]) = w4p;
      }
    {
      h16x8 pf0 = *(const h16x8*)(&Pw[l16 * LPS + quad * 8]);
      h16x8 pf1 = *(const h16x8*)(&Pw[(16 + l16) * LPS + quad * 8]);
      __builtin_amdgcn_s_setprio(1);
      #pragma unroll
      for (int nfo = 0; nfo < 6; nfo++) {
        h16x8 vfr = *(const h16x8*)(&Vtg[(nfo * 16 + l16) * LVT + quad * 8]);
        o[0][nfo] = __builtin_amdgcn_mfma_f32_16x16x32_f16(vfr, pf0, o[0][nfo], 0, 0, 0);
        o[1][nfo] = __builtin_amdgcn_mfma_f32_16x16x32_f16(vfr, pf1, o[1][nfo], 0, 0, 0);
      }
      __builtin_amdgcn_s_setprio(0);
    }

    // ---- P half1 write (kf 2,3; s dies) -> LOADT(i+1) -> PV half1 ----
    #pragma unroll
    for (int mf = 0; mf < 2; mf++)
      #pragma unroll
      for (int kf2 = 0; kf2 < 2; kf2++) {
        const int kf = 2 + kf2;
        fp16x2 a2 = __builtin_amdgcn_cvt_pkrtz(s[mf][kf][0], s[mf][kf][1]);
        fp16x2 b2 = __builtin_amdgcn_cvt_pkrtz(s[mf][kf][2], s[mf][kf][3]);
        fp16x4 w4p; w4p[0] = a2[0]; w4p[1] = a2[1]; w4p[2] = b2[0]; w4p[3] = b2[1];
        *(fp16x4*)(&Pw[(mf * 16 + l16) * LPS + kf2 * 16 + quad * 4]) = w4p;
      }
    if (i + 1 < 16) LOADT(t0 + i + 1);   // s dead; kR/vR live only from here
    {
      h16x8 pf0 = *(const h16x8*)(&Pw[l16 * LPS + quad * 8]);
      h16x8 pf1 = *(const h16x8*)(&Pw[(16 + l16) * LPS + quad * 8]);
      __builtin_amdgcn_s_setprio(1);
      #pragma unroll
      for (int nfo = 0; nfo < 6; nfo++) {
        h16x8 vfr = *(const h16x8*)(&Vtg[(nfo * 16 + l16) * LVT + 32 + quad * 8]);
        o[0][nfo] = __builtin_amdgcn_mfma_f32_16x16x32_f16(vfr, pf0, o[0][nfo], 0, 0, 0);
        o[1][nfo] = __builtin_amdgcn_mfma_f32_16x16x32_f16(vfr, pf1, o[1][nfo], 0, 0, 0);
      }
      __builtin_amdgcn_s_setprio(0);
    }

    // ---- staging: write tile i+1 ----
    if (i + 1 < 16) {
      __syncthreads();                 // group done reading tile i
      WRITET();
      __syncthreads();                 // tile i+1 ready
    }
  }
#undef LOADT
#undef WRITET

  // ---- flash-combine merge of the two KV-group partials ----
  __syncthreads();                     // everyone done with Ks/Vt
  #pragma unroll
  for (int mf = 0; mf < 2; mf++) {
    lrow[mf] += __shfl_xor(lrow[mf], 16);
    lrow[mf] += __shfl_xor(lrow[mf], 32);
  }
  float* Ms = (float*)SMEM;            // 4 slots x 32 rows x 96 f32 = 48KB
  float* MLs = (float*)Psb;            // 4 slots x 32 rows x 2 f32

  if (g == 1) {
    float* os = Ms + w4 * (32 * 96);
    #pragma unroll
    for (int mf = 0; mf < 2; mf++) {
      #pragma unroll
      for (int nfo = 0; nfo < 6; nfo++)
        *(f32x4*)(&os[(mf * 16 + l16) * 96 + nfo * 16 + quad * 4]) = o[mf][nfo];
      if (quad == 0) {
        MLs[(w4 * 32 + mf * 16 + l16) * 2 + 0] = m_raw[mf];
        MLs[(w4 * 32 + mf * 16 + l16) * 2 + 1] = lrow[mf];
      }
    }
  }
  __syncthreads();
  if (g == 0) {
    float* os = Ms + w4 * (32 * 96);
    #pragma unroll
    for (int mf = 0; mf < 2; mf++) {
      const float m1 = MLs[(w4 * 32 + mf * 16 + l16) * 2 + 0];
      const float l1 = MLs[(w4 * 32 + mf * 16 + l16) * 2 + 1];
      const float mm = fmaxf(m_raw[mf], m1);
      const float e0 = exp2f(sc * (m_raw[mf] - mm));
      const float e1 = exp2f(sc * (m1 - mm));
      const float inv = 1.0f / (e0 * lrow[mf] + e1 * l1);
      const float a0 = e0 * inv, a1 = e1 * inv;
      u16* Ob = O + batch_off + (size_t)(qbase + mf * 16 + l16) * 768 + h * 96;
      #pragma unroll
      for (int nfo = 0; nfo < 6; nfo++) {
        f32x4 o1 = *(const f32x4*)(&os[(mf * 16 + l16) * 96 + nfo * 16 + quad * 4]);
        float v0 = a0 * o[mf][nfo][0] + a1 * o1[0];
        float v1 = a0 * o[mf][nfo][1] + a1 * o1[1];
        float v2 = a0 * o[mf][nfo][2] + a1 * o1[2];
        float v3 = a0 * o[mf][nfo][3] + a1 * o1[3];
        fp16x2 lo = __builtin_amdgcn_cvt_pkrtz(v0, v1);
        fp16x2 hi = __builtin_amdgcn_cvt_pkrtz(v2, v3);
        *(fp16x2*)(&Ob[nfo * 16 + quad * 4]) = lo;
        *(fp16x2*)(&Ob[nfo * 16 + quad * 4 + 2]) = hi;
      }
    }
  }
}

// ---------------------------------------------------------------------------
extern "C" void kernel_launch(void* const* d_in, const int* in_sizes, int n_in,
                              void* d_out, int out_size, void* d_ws, size_t ws_size,
                              hipStream_t stream) {
  const float* Xq = (const float*)d_in[0];
  const float* Xk = (const float*)d_in[1];
  const float* Xv = (const float*)d_in[2];
  const float* Wq = (const float*)d_in[3];
  const float* bq = (const float*)d_in[4];
  const float* Wk = (const float*)d_in[5];
  const float* bk = (const float*)d_in[6];
  const float* Wv = (const float*)d_in[7];
  const float* bv = (const float*)d_in[8];
  const float* Wo = (const float*)d_in[9];
  const float* bo = (const float*)d_in[10];

  u16* wsu = (u16*)d_ws;
  u16* WT   = wsu;                    // WqT | WkT | WvT, 589824 each
  u16* WoT  = wsu + 3 * 589824;
  u16* Q16  = wsu + 4 * 589824;       // 12.6 MB
  u16* Xk16 = Q16 + 6291456;          // 12.6 MB
  u16* Xv16 = Xk16 + 6291456;         // 12.6 MB
  u16* Xq16 = Xv16 + 6291456;         // 12.6 MB (total 55.05 MB)

  u16* outu = (u16*)d_out;
  u16* VTb = outu;                   // V^T f16 [4][768][2048]
  u16* K16 = outu + 6291456;         // K f16 rowmajor

  u16* A16 = Xk16;                   // attn out overlays Xk16 (dead after
                                     // gemm_qkv) -- d_in never written.

  prep_kernel<<<9648, 256, 0, stream>>>(
      Wq, Wk, Wv, Wo, Xk, Xv, Xq,
      WT, WT + 589824, WT + 2 * 589824, WoT, Xk16, Xv16, Xq16);
  gemm_qkv<<<dim3(64, 6, 3), 256, 0, stream>>>(
      Xq16, Xk16, Xv16, WT, bq, bk, bv, Q16, K16, VTb);
  attn_kernel<<<dim3(16, 32), 512, 0, stream>>>(Q16, K16, VTb, A16);
  gemm_o<<<dim3(64, 6), 256, 0, stream>>>(A16, WoT, bo, (float*)d_out);
}